// Round 3
// baseline (646.062 us; speedup 1.0000x reference)
//
#include <hip/hip_runtime.h>
#include <hip/hip_bf16.h>

typedef unsigned short u16;
typedef __attribute__((ext_vector_type(8))) short short8;
typedef __attribute__((ext_vector_type(4))) float floatx4;

#define BSZ   4
#define CDIM  512
#define NDIM  512
#define SDIM  64
#define LEN   8192
#define GCH   16
#define TCH   (LEN / GCH)

__device__ __forceinline__ u16 f2bf(float x) {
    unsigned int u = __float_as_uint(x);
    unsigned int r = (u + 0x7FFFu + ((u >> 16) & 1u)) >> 16;
    return (u16)r;
}
__device__ __forceinline__ float bf2f(u16 h) {
    return __uint_as_float(((unsigned int)h) << 16);
}

#define GLL16(g, l)                                                          \
    __builtin_amdgcn_global_load_lds(                                        \
        (const __attribute__((address_space(1))) unsigned int*)(g),          \
        (__attribute__((address_space(3))) unsigned int*)(l), 16, 0, 0)

// ---------------------------------------------------------------------------
// Split both weight matrices fp32 -> (hi,lo) bf16 in one launch.
// grid 512: blocks 0-255 -> Bm, 256-511 -> Cm. 262144 elems each.
// ---------------------------------------------------------------------------
__global__ __launch_bounds__(256) void convert_split2(const float* __restrict__ B,
                                                      const float* __restrict__ C,
                                                      u16* __restrict__ bh, u16* __restrict__ bl,
                                                      u16* __restrict__ ch, u16* __restrict__ cl) {
    int i = (blockIdx.x * 256 + threadIdx.x) * 4;
    const float* src; u16 *dh, *dl;
    if (i < 262144) { src = B; dh = bh; dl = bl; }
    else            { src = C; dh = ch; dl = cl; i -= 262144; }
    float4 v = *(const float4*)&src[i];
    float f[4] = {v.x, v.y, v.z, v.w};
    ushort4 h, l;
    u16* hp = (u16*)&h; u16* lp = (u16*)&l;
#pragma unroll
    for (int q = 0; q < 4; ++q) {
        u16 hb = f2bf(f[q]);
        hp[q] = hb;
        lp[q] = f2bf(f[q] - bf2f(hb));
    }
    *(ushort4*)&dh[i] = h;
    *(ushort4*)&dl[i] = l;
}

// ---------------------------------------------------------------------------
// Transposed split: src [B][R=512][L=8192] fp32 -> dhi/dlo [B][L][512] bf16.
// ---------------------------------------------------------------------------
__global__ __launch_bounds__(256) void transpose_split(const float* __restrict__ src,
                                                       u16* __restrict__ dhi,
                                                       u16* __restrict__ dlo) {
    __shared__ float tile[64][65];
    const int b  = blockIdx.z;
    const int r0 = blockIdx.y * 64;
    const int c0 = blockIdx.x * 64;
    const int t  = threadIdx.x;
    const float* s = src + (size_t)b * 512 * 8192;
#pragma unroll
    for (int p = 0; p < 4; ++p) {
        int r = (t >> 4) + p * 16;
        float4 v = *(const float4*)&s[(size_t)(r0 + r) * 8192 + c0 + (t & 15) * 4];
        tile[r][(t & 15) * 4 + 0] = v.x;
        tile[r][(t & 15) * 4 + 1] = v.y;
        tile[r][(t & 15) * 4 + 2] = v.z;
        tile[r][(t & 15) * 4 + 3] = v.w;
    }
    __syncthreads();
#pragma unroll
    for (int p = 0; p < 4; ++p) {
        int i  = (t >> 4) + p * 16;
        int cb = (t & 15) * 4;
        ushort4 h, l;
        u16* hp = (u16*)&h; u16* lp = (u16*)&l;
#pragma unroll
        for (int q = 0; q < 4; ++q) {
            float x = tile[cb + q][i];
            u16 hb = f2bf(x);
            hp[q] = hb;
            lp[q] = f2bf(x - bf2f(hb));
        }
        size_t o = ((size_t)b * 8192 + c0 + i) * 512 + r0 + cb;
        *(ushort4*)&dhi[o] = h;
        *(ushort4*)&dlo[o] = l;
    }
}

// ---------------------------------------------------------------------------
// Split-bf16 MFMA GEMM, fused 3-product K-loop:
// Y[b][m][l] = sum_k (Ahi+Alo)[m][k] * (Xhi+Xlo)[b][l][k]  (dropping lo*lo)
// 128x128 tile, BK=32, 48 MFMA per K-iter.
// ---------------------------------------------------------------------------
__global__ __launch_bounds__(256) void gemm_mfma(const u16* __restrict__ Ahi,
                                                 const u16* __restrict__ Alo,
                                                 const u16* __restrict__ Xhi,
                                                 const u16* __restrict__ Xlo,
                                                 float* __restrict__ Y) {
    __shared__ u16 AsH[128 * 32];
    __shared__ u16 AsL[128 * 32];
    __shared__ u16 XsH[128 * 32];
    __shared__ u16 XsL[128 * 32];
    const int b    = blockIdx.z;
    const int m0   = blockIdx.y * 128;
    const int l0   = blockIdx.x * 128;
    const int t    = threadIdx.x;
    const int w    = t >> 6;
    const int lane = t & 63;
    const int mq   = (w >> 1) * 64;
    const int lq   = (w & 1) * 64;

    const u16* XbH = Xhi + (size_t)b * 8192 * 512;
    const u16* XbL = Xlo + (size_t)b * 8192 * 512;

    const size_t a_off = (size_t)(m0 + 32 * w + (lane >> 2)) * 512 + (lane & 3) * 8;
    const size_t x_off = (size_t)(l0 + 32 * w + (lane >> 2)) * 512 + (lane & 3) * 8;
    const int    wofs  = w * 1024;

    floatx4 acc[4][4];
#pragma unroll
    for (int i = 0; i < 4; ++i)
#pragma unroll
        for (int j = 0; j < 4; ++j) acc[i][j] = (floatx4)0.f;

    const int fr = lane & 15;
    const int fk = (lane >> 4) * 8;

    for (int k0 = 0; k0 < 512; k0 += 32) {
        __syncthreads();
        GLL16(Ahi + a_off + k0, AsH + wofs);
        GLL16(Ahi + a_off + 16 * 512 + k0, AsH + wofs + 512);
        GLL16(Alo + a_off + k0, AsL + wofs);
        GLL16(Alo + a_off + 16 * 512 + k0, AsL + wofs + 512);
        GLL16(XbH + x_off + k0, XsH + wofs);
        GLL16(XbH + x_off + 16 * 512 + k0, XsH + wofs + 512);
        GLL16(XbL + x_off + k0, XsL + wofs);
        GLL16(XbL + x_off + 16 * 512 + k0, XsL + wofs + 512);
        __syncthreads();
        short8 ah[4], al[4];
#pragma unroll
        for (int i = 0; i < 4; ++i) {
            ah[i] = *(const short8*)&AsH[(mq + i * 16 + fr) * 32 + fk];
            al[i] = *(const short8*)&AsL[(mq + i * 16 + fr) * 32 + fk];
        }
#pragma unroll
        for (int j = 0; j < 4; ++j) {
            short8 xh = *(const short8*)&XsH[(lq + j * 16 + fr) * 32 + fk];
            short8 xl = *(const short8*)&XsL[(lq + j * 16 + fr) * 32 + fk];
#pragma unroll
            for (int i = 0; i < 4; ++i) {
                acc[i][j] = __builtin_amdgcn_mfma_f32_16x16x32_bf16(ah[i], xh, acc[i][j], 0, 0, 0);
                acc[i][j] = __builtin_amdgcn_mfma_f32_16x16x32_bf16(al[i], xh, acc[i][j], 0, 0, 0);
                acc[i][j] = __builtin_amdgcn_mfma_f32_16x16x32_bf16(ah[i], xl, acc[i][j], 0, 0, 0);
            }
        }
    }

    float* Yb = Y + (size_t)b * 512 * 8192;
#pragma unroll
    for (int i = 0; i < 4; ++i)
#pragma unroll
        for (int j = 0; j < 4; ++j)
#pragma unroll
            for (int r = 0; r < 4; ++r) {
                int mg = m0 + mq + i * 16 + (lane >> 4) * 4 + r;
                int lg = l0 + lq + j * 16 + (lane & 15);
                Yb[(size_t)mg * 8192 + lg] = acc[i][j][r];
            }
}

// ---------------------------------------------------------------------------
// Phase A: chunk-local scan via 2nd-order real recurrence (2 fma/step):
//   u[t] = c1*u[t-1] + c2*u[t-2] + x[t],  c1 = 2*ea*cos(w), c2 = -ea^2
// End conversion (exact, no division): hr = u - ea*cos(w)*u1, hi = ea*sin(w)*u1.
// 4 waves/block, one chunk per wave. x read as wave-uniform broadcast loads.
// ---------------------------------------------------------------------------
__global__ __launch_bounds__(256) void scan_states(const float* __restrict__ dAr,
                                                   const float* __restrict__ dAi,
                                                   const float* __restrict__ x,
                                                   float* __restrict__ states) {
    const int wid  = threadIdx.x >> 6;
    const int id   = blockIdx.x * 4 + wid;       // chunk id
    const int k    = id & (GCH - 1);
    const int n    = (id >> 4) & (NDIM - 1);
    const int b    = id >> 13;
    const int lane = threadIdx.x & 63;           // = s
    const float a  = dAr[n * SDIM + lane], wv = dAi[n * SDIM + lane];
    const float ea = __expf(a);
    float sw, cw;
    __sincosf(wv, &sw, &cw);
    const float c1 = 2.f * ea * cw;
    const float c2 = -ea * ea;
    const float* xp = x + (((size_t)b * NDIM + n) * LEN) + k * TCH;

    float u = 0.f, u1 = 0.f;
    for (int t0 = 0; t0 < TCH; t0 += 32) {
        float xr[32];
#pragma unroll
        for (int q = 0; q < 8; ++q)
            *(float4*)&xr[q * 4] = *(const float4*)&xp[t0 + q * 4];
#pragma unroll
        for (int tt = 0; tt < 32; ++tt) {
            float un = fmaf(c1, u, fmaf(c2, u1, xr[tt]));
            u1 = u; u = un;
        }
    }
    float hr = fmaf(-ea * cw, u1, u);
    float hi = ea * sw * u1;
    ((float2*)states)[(size_t)id * SDIM + lane] = make_float2(hr, hi);
}

// ---------------------------------------------------------------------------
// Phase B: sequential prefix over chunks per (b,n,s) — complex basis.
// ---------------------------------------------------------------------------
__global__ __launch_bounds__(256) void scan_combine(const float* __restrict__ dAr,
                                                    const float* __restrict__ dAi,
                                                    float* __restrict__ states) {
    const int tid = blockIdx.x * 256 + threadIdx.x;
    const int s  = tid & (SDIM - 1);
    const int bn = tid >> 6;
    const int n  = bn & (NDIM - 1);
    const float a = dAr[n * SDIM + s], w = dAi[n * SDIM + s];
    const float eaT = expf(a * (float)TCH);
    float sT, cT;
    sincosf(w * (float)TCH, &sT, &cT);
    const float zTr = eaT * cT, zTi = eaT * sT;
    float2* st = (float2*)states;
    const size_t base = (size_t)bn * GCH * SDIM + s;
    float Hr = 0.f, Hi = 0.f;
    for (int k = 0; k < GCH; ++k) {
        float2 le = st[base + (size_t)k * SDIM];
        st[base + (size_t)k * SDIM] = make_float2(Hr, Hi);
        float nHr = fmaf(zTr, Hr, fmaf(-zTi, Hi, le.x));
        float nHi = fmaf(zTi, Hr, fmaf(zTr, Hi, le.y));
        Hr = nHr; Hi = nHi;
    }
}

// ---------------------------------------------------------------------------
// Phase C: scan from H_before, emit y in-place over x.
// 4 waves/block (one chunk each). No barriers: cmat is per-wave, RAW within
// wave is handled by lgkmcnt. x read as wave-uniform broadcast loads.
// ---------------------------------------------------------------------------
__global__ __launch_bounds__(256) void scan_out(const float* __restrict__ dAr,
                                                const float* __restrict__ dAi,
                                                const float* __restrict__ E,
                                                const float* __restrict__ states,
                                                float* __restrict__ xy) {
    __shared__ float cmat[4][32 * 65];
    const int wid  = threadIdx.x >> 6;
    const int id   = blockIdx.x * 4 + wid;
    const int k    = id & (GCH - 1);
    const int n    = (id >> 4) & (NDIM - 1);
    const int b    = id >> 13;
    const int lane = threadIdx.x & 63;           // = s
    const float a  = dAr[n * SDIM + lane], wv = dAi[n * SDIM + lane];
    const float ea = __expf(a);
    float sw, cw;
    __sincosf(wv, &sw, &cw);
    const float zr = ea * cw, zi = ea * sw;
    const float Ew = E[n * SDIM + lane];
    float2 H = ((const float2*)states)[(size_t)id * SDIM + lane];
    float hr = H.x, hi = H.y;
    float* xp = xy + (((size_t)b * NDIM + n) * LEN) + k * TCH;
    float* cm = cmat[wid];
    const int row = lane & 31, sbase = (lane >> 5) << 5;

    for (int t0 = 0; t0 < TCH; t0 += 32) {
        float xr[32];
#pragma unroll
        for (int q = 0; q < 8; ++q)
            *(float4*)&xr[q * 4] = *(const float4*)&xp[t0 + q * 4];
#pragma unroll
        for (int tt = 0; tt < 32; ++tt) {
            float nhr = fmaf(zr, hr, fmaf(-zi, hi, xr[tt]));
            float nhi = fmaf(zi, hr, zr * hi);
            hr = nhr; hi = nhi;
            cm[tt * 65 + lane] = Ew * hr;
        }
        float acc = 0.f;
#pragma unroll
        for (int i = 0; i < 32; ++i) acc += cm[row * 65 + sbase + i];
        acc += __shfl_xor(acc, 32, 64);
        if (lane < 32) xp[t0 + lane] = acc;
    }
}

// ---------------------------------------------------------------------------
extern "C" void kernel_launch(void* const* d_in, const int* in_sizes, int n_in,
                              void* d_out, int out_size, void* d_ws, size_t ws_size,
                              hipStream_t stream) {
    const float* input = (const float*)d_in[0];  // [B, C, L]
    const float* dAr   = (const float*)d_in[1];
    const float* dAi   = (const float*)d_in[2];
    const float* Bm    = (const float*)d_in[3];  // [N, C]
    const float* Cm    = (const float*)d_in[4];  // [C, N]
    const float* E     = (const float*)d_in[5];
    float* out = (float*)d_out;

    char* ws = (char*)d_ws;
    float* wx  = (float*)ws;                       // 64 MiB: x then y in-place
    u16* xthi  = (u16*)(ws + 67108864);            // 32 MiB
    u16* xtlo  = (u16*)(ws + 100663296);           // 32 MiB
    u16* wbhi  = (u16*)(ws + 134217728);
    u16* wblo  = (u16*)(ws + 134742016);
    u16* wchi  = (u16*)(ws + 135266304);
    u16* wclo  = (u16*)(ws + 135790592);
    float* wst = (float*)(ws + 67108864);          // states overlay xthi (dead then)

    convert_split2<<<512, 256, 0, stream>>>(Bm, Cm, wbhi, wblo, wchi, wclo);
    transpose_split<<<dim3(128, 8, BSZ), 256, 0, stream>>>(input, xthi, xtlo);
    gemm_mfma<<<dim3(64, 4, BSZ), 256, 0, stream>>>(wbhi, wblo, xthi, xtlo, wx);
    scan_states<<<BSZ * NDIM * GCH / 4, 256, 0, stream>>>(dAr, dAi, wx, wst);
    scan_combine<<<(BSZ * NDIM * SDIM) / 256, 256, 0, stream>>>(dAr, dAi, wst);
    scan_out<<<BSZ * NDIM * GCH / 4, 256, 0, stream>>>(dAr, dAi, E, wst, wx);
    transpose_split<<<dim3(128, 8, BSZ), 256, 0, stream>>>(wx, xthi, xtlo);
    gemm_mfma<<<dim3(64, 4, BSZ), 256, 0, stream>>>(wchi, wclo, xthi, xtlo, out);
}

// Round 4
// 398.412 us; speedup vs baseline: 1.6216x; 1.6216x over previous
//
#include <hip/hip_runtime.h>
#include <hip/hip_bf16.h>

typedef unsigned short u16;
typedef __attribute__((ext_vector_type(8))) short short8;
typedef __attribute__((ext_vector_type(4))) float floatx4;

#define BSZ   4
#define CDIM  512
#define NDIM  512
#define SDIM  64
#define LEN   8192
#define TCH   128            // chunk length
#define JCH   64             // chunks per (b,n)

__device__ __forceinline__ u16 f2bf(float x) {
    unsigned int u = __float_as_uint(x);
    unsigned int r = (u + 0x7FFFu + ((u >> 16) & 1u)) >> 16;
    return (u16)r;
}
__device__ __forceinline__ float bf2f(u16 h) {
    return __uint_as_float(((unsigned int)h) << 16);
}

#define GLL16(g, l)                                                          \
    __builtin_amdgcn_global_load_lds(                                        \
        (const __attribute__((address_space(1))) unsigned int*)(g),          \
        (__attribute__((address_space(3))) unsigned int*)(l), 16, 0, 0)

// ---------------------------------------------------------------------------
// Split both weight matrices fp32 -> (hi,lo) bf16.
// ---------------------------------------------------------------------------
__global__ __launch_bounds__(256) void convert_split2(const float* __restrict__ B,
                                                      const float* __restrict__ C,
                                                      u16* __restrict__ bh, u16* __restrict__ bl,
                                                      u16* __restrict__ ch, u16* __restrict__ cl) {
    int i = (blockIdx.x * 256 + threadIdx.x) * 4;
    const float* src; u16 *dh, *dl;
    if (i < 262144) { src = B; dh = bh; dl = bl; }
    else            { src = C; dh = ch; dl = cl; i -= 262144; }
    float4 v = *(const float4*)&src[i];
    float f[4] = {v.x, v.y, v.z, v.w};
    ushort4 h, l;
    u16* hp = (u16*)&h; u16* lp = (u16*)&l;
#pragma unroll
    for (int q = 0; q < 4; ++q) {
        u16 hb = f2bf(f[q]);
        hp[q] = hb;
        lp[q] = f2bf(f[q] - bf2f(hb));
    }
    *(ushort4*)&dh[i] = h;
    *(ushort4*)&dl[i] = l;
}

// ---------------------------------------------------------------------------
// Kn[n][d] = sum_s E[n,s] * exp(a*d) * cos(w*d),  d = 0..127  (fp32)
// ---------------------------------------------------------------------------
__global__ __launch_bounds__(256) void kern_K(const float* __restrict__ dAr,
                                              const float* __restrict__ dAi,
                                              const float* __restrict__ E,
                                              float* __restrict__ Kn) {
    const int id = blockIdx.x * 256 + threadIdx.x;   // n*128 + d
    const int n = id >> 7;
    const float d = (float)(id & 127);
    float acc = 0.f;
    for (int s = 0; s < 64; ++s) {
        float a = dAr[n * 64 + s], w = dAi[n * 64 + s];
        acc = fmaf(E[n * 64 + s], __expf(a * d) * __cosf(w * d), acc);
    }
    Kn[id] = acc;
}

// ---------------------------------------------------------------------------
// Fill Afull [n][t=128][k=256] and WW [n][q=128][tau=128] (bf16).
//  Afull k<128 : Toep[t][tau=k] = K[n][t-k] (k<=t) else 0
//  Afull k>=128: q=k-128, s=q&63: M = E*e^{a(t+1)} * (q<64 ? cos : -sin)(w(t+1))
//  WW: s=q&63, d=127-tau: e^{a d} * (q<64 ? cos : sin)(w d)
// ---------------------------------------------------------------------------
__global__ __launch_bounds__(256) void kern_AW(const float* __restrict__ dAr,
                                               const float* __restrict__ dAi,
                                               const float* __restrict__ E,
                                               const float* __restrict__ Kn,
                                               u16* __restrict__ Af,
                                               u16* __restrict__ WW) {
    int id = blockIdx.x * 256 + threadIdx.x;
    if (id < 16777216) {                       // Afull: n*(128*256) + t*256 + k
        const int n = id >> 15;
        const int t = (id >> 8) & 127;
        const int k = id & 255;
        float val;
        if (k < 128) {
            val = (k <= t) ? Kn[n * 128 + (t - k)] : 0.f;
        } else {
            const int q = k - 128, s = q & 63;
            const float a = dAr[n * 64 + s], w = dAi[n * 64 + s];
            const float tp1 = (float)(t + 1);
            float sn, cs;
            __sincosf(w * tp1, &sn, &cs);
            const float ea = __expf(a * tp1) * E[n * 64 + s];
            val = (q < 64) ? ea * cs : -ea * sn;
        }
        Af[id] = f2bf(val);
    } else {                                   // WW: n*(128*128) + q*128 + tau
        int wid = id - 16777216;
        const int n = wid >> 14;
        const int q = (wid >> 7) & 127, s = q & 63;
        const int tau = wid & 127;
        const float a = dAr[n * 64 + s], w = dAi[n * 64 + s];
        const float d = (float)(127 - tau);
        float sn, cs;
        __sincosf(w * d, &sn, &cs);
        const float ea = __expf(a * d);
        WW[wid] = f2bf((q < 64) ? ea * cs : ea * sn);
    }
}

// ---------------------------------------------------------------------------
// Transposed split: src [B][512][8192] fp32 -> dhi/dlo [B][8192][512] bf16.
// ---------------------------------------------------------------------------
__global__ __launch_bounds__(256) void transpose_split(const float* __restrict__ src,
                                                       u16* __restrict__ dhi,
                                                       u16* __restrict__ dlo) {
    __shared__ float tile[64][65];
    const int b  = blockIdx.z;
    const int r0 = blockIdx.y * 64;
    const int c0 = blockIdx.x * 64;
    const int t  = threadIdx.x;
    const float* s = src + (size_t)b * 512 * 8192;
#pragma unroll
    for (int p = 0; p < 4; ++p) {
        int r = (t >> 4) + p * 16;
        float4 v = *(const float4*)&s[(size_t)(r0 + r) * 8192 + c0 + (t & 15) * 4];
        tile[r][(t & 15) * 4 + 0] = v.x;
        tile[r][(t & 15) * 4 + 1] = v.y;
        tile[r][(t & 15) * 4 + 2] = v.z;
        tile[r][(t & 15) * 4 + 3] = v.w;
    }
    __syncthreads();
#pragma unroll
    for (int p = 0; p < 4; ++p) {
        int i  = (t >> 4) + p * 16;
        int cb = (t & 15) * 4;
        ushort4 h, l;
        u16* hp = (u16*)&h; u16* lp = (u16*)&l;
#pragma unroll
        for (int q = 0; q < 4; ++q) {
            float x = tile[cb + q][i];
            u16 hb = f2bf(x);
            hp[q] = hb;
            lp[q] = f2bf(x - bf2f(hb));
        }
        size_t o = ((size_t)b * 8192 + c0 + i) * 512 + r0 + cb;
        *(ushort4*)&dhi[o] = h;
        *(ushort4*)&dlo[o] = l;
    }
}

// ---------------------------------------------------------------------------
// Split-bf16 MFMA GEMM (r2 proven 3-phase), bf16 output:
// xbf[b][m][l] = sum_k (Ahi+Alo)[m][k]*(Xhi+Xlo)[b][l][k]
// ---------------------------------------------------------------------------
__global__ __launch_bounds__(256) void gemm_mfma_bf16(const u16* __restrict__ Ahi,
                                                      const u16* __restrict__ Alo,
                                                      const u16* __restrict__ Xhi,
                                                      const u16* __restrict__ Xlo,
                                                      u16* __restrict__ Y) {
    __shared__ u16 As[128 * 32];
    __shared__ u16 Xs[128 * 32];
    const int b    = blockIdx.z;
    const int m0   = blockIdx.y * 128;
    const int l0   = blockIdx.x * 128;
    const int t    = threadIdx.x;
    const int w    = t >> 6;
    const int lane = t & 63;
    const int mq   = (w >> 1) * 64;
    const int lq   = (w & 1) * 64;
    const u16* Xb_hi = Xhi + (size_t)b * 8192 * 512;
    const u16* Xb_lo = Xlo + (size_t)b * 8192 * 512;
    const size_t a_off = (size_t)(m0 + 32 * w + (lane >> 2)) * 512 + (lane & 3) * 8;
    const size_t x_off = (size_t)(l0 + 32 * w + (lane >> 2)) * 512 + (lane & 3) * 8;
    u16* AsW = As + w * 1024;
    u16* XsW = Xs + w * 1024;

    floatx4 acc[4][4];
#pragma unroll
    for (int i = 0; i < 4; ++i)
#pragma unroll
        for (int j = 0; j < 4; ++j) acc[i][j] = (floatx4)0.f;
    const int fr = lane & 15;
    const int fk = (lane >> 4) * 8;

#pragma unroll
    for (int p = 0; p < 3; ++p) {
        const u16* Ap = (p == 2) ? Alo : Ahi;
        const u16* Xp = (p == 1) ? Xb_lo : Xb_hi;
        for (int k0 = 0; k0 < 512; k0 += 32) {
            __syncthreads();
            GLL16(Ap + a_off + k0, AsW);
            GLL16(Ap + a_off + 16 * 512 + k0, AsW + 512);
            GLL16(Xp + x_off + k0, XsW);
            GLL16(Xp + x_off + 16 * 512 + k0, XsW + 512);
            __syncthreads();
            short8 af[4], bf[4];
#pragma unroll
            for (int i = 0; i < 4; ++i) {
                af[i] = *(const short8*)&As[(mq + i * 16 + fr) * 32 + fk];
                bf[i] = *(const short8*)&Xs[(lq + i * 16 + fr) * 32 + fk];
            }
#pragma unroll
            for (int i = 0; i < 4; ++i)
#pragma unroll
                for (int j = 0; j < 4; ++j)
                    acc[i][j] = __builtin_amdgcn_mfma_f32_16x16x32_bf16(
                        af[i], bf[j], acc[i][j], 0, 0, 0);
        }
    }
    u16* Yb = Y + (size_t)b * 512 * 8192;
#pragma unroll
    for (int i = 0; i < 4; ++i)
#pragma unroll
        for (int j = 0; j < 4; ++j)
#pragma unroll
            for (int r = 0; r < 4; ++r) {
                int mg = m0 + mq + i * 16 + (lane >> 4) * 4 + r;
                int lg = l0 + lq + j * 16 + (lane & 15);
                Yb[(size_t)mg * 8192 + lg] = f2bf(acc[i][j][r]);
            }
}

// ---------------------------------------------------------------------------
// Same GEMM, fp32 output (final projection).
// ---------------------------------------------------------------------------
__global__ __launch_bounds__(256) void gemm_mfma_f32(const u16* __restrict__ Ahi,
                                                     const u16* __restrict__ Alo,
                                                     const u16* __restrict__ Xhi,
                                                     const u16* __restrict__ Xlo,
                                                     float* __restrict__ Y) {
    __shared__ u16 As[128 * 32];
    __shared__ u16 Xs[128 * 32];
    const int b    = blockIdx.z;
    const int m0   = blockIdx.y * 128;
    const int l0   = blockIdx.x * 128;
    const int t    = threadIdx.x;
    const int w    = t >> 6;
    const int lane = t & 63;
    const int mq   = (w >> 1) * 64;
    const int lq   = (w & 1) * 64;
    const u16* Xb_hi = Xhi + (size_t)b * 8192 * 512;
    const u16* Xb_lo = Xlo + (size_t)b * 8192 * 512;
    const size_t a_off = (size_t)(m0 + 32 * w + (lane >> 2)) * 512 + (lane & 3) * 8;
    const size_t x_off = (size_t)(l0 + 32 * w + (lane >> 2)) * 512 + (lane & 3) * 8;
    u16* AsW = As + w * 1024;
    u16* XsW = Xs + w * 1024;

    floatx4 acc[4][4];
#pragma unroll
    for (int i = 0; i < 4; ++i)
#pragma unroll
        for (int j = 0; j < 4; ++j) acc[i][j] = (floatx4)0.f;
    const int fr = lane & 15;
    const int fk = (lane >> 4) * 8;

#pragma unroll
    for (int p = 0; p < 3; ++p) {
        const u16* Ap = (p == 2) ? Alo : Ahi;
        const u16* Xp = (p == 1) ? Xb_lo : Xb_hi;
        for (int k0 = 0; k0 < 512; k0 += 32) {
            __syncthreads();
            GLL16(Ap + a_off + k0, AsW);
            GLL16(Ap + a_off + 16 * 512 + k0, AsW + 512);
            GLL16(Xp + x_off + k0, XsW);
            GLL16(Xp + x_off + 16 * 512 + k0, XsW + 512);
            __syncthreads();
            short8 af[4], bf[4];
#pragma unroll
            for (int i = 0; i < 4; ++i) {
                af[i] = *(const short8*)&As[(mq + i * 16 + fr) * 32 + fk];
                bf[i] = *(const short8*)&Xs[(lq + i * 16 + fr) * 32 + fk];
            }
#pragma unroll
            for (int i = 0; i < 4; ++i)
#pragma unroll
                for (int j = 0; j < 4; ++j)
                    acc[i][j] = __builtin_amdgcn_mfma_f32_16x16x32_bf16(
                        af[i], bf[j], acc[i][j], 0, 0, 0);
        }
    }
    float* Yb = Y + (size_t)b * 512 * 8192;
#pragma unroll
    for (int i = 0; i < 4; ++i)
#pragma unroll
        for (int j = 0; j < 4; ++j)
#pragma unroll
            for (int r = 0; r < 4; ++r) {
                int mg = m0 + mq + i * 16 + (lane >> 4) * 4 + r;
                int lg = l0 + lq + j * 16 + (lane & 15);
                Yb[(size_t)mg * 8192 + lg] = acc[i][j][r];
            }
}

// ---------------------------------------------------------------------------
// SE-GEMM: per n, SE[c][q] = sum_tau x[c][tau] * WW[n][q][tau]
//   c = b*64+j (256 cols -> rows of output), q = 0..127, K = 128.
// grid (2, 512): 128 c-rows per block, all 128 q-cols.
// ---------------------------------------------------------------------------
__global__ __launch_bounds__(256) void se_gemm(const u16* __restrict__ xbf,
                                               const u16* __restrict__ WW,
                                               u16* __restrict__ SEf) {
    __shared__ u16 As[128 * 32];   // x rows (c)
    __shared__ u16 Bs[128 * 32];   // WW rows (q)
    const int n  = blockIdx.y;
    const int c0 = blockIdx.x * 128;
    const int t  = threadIdx.x;
    const int w  = t >> 6, lane = t & 63;
    const int mq = (w >> 1) * 64;   // row (c) quadrant
    const int lq = (w & 1) * 64;    // col (q) quadrant
    const int ar0 = 32 * w + (lane >> 2);
    const int kq8 = (lane & 3) * 8;
    const int c_a0 = c0 + ar0, c_a1 = c_a0 + 16;
    const size_t xrow0 = ((size_t)(c_a0 >> 6) * 512 + n) * 8192 + (size_t)(c_a0 & 63) * 128 + kq8;
    const size_t xrow1 = ((size_t)(c_a1 >> 6) * 512 + n) * 8192 + (size_t)(c_a1 & 63) * 128 + kq8;
    const size_t brow0 = (size_t)n * 16384 + (size_t)ar0 * 128 + kq8;
    const size_t brow1 = brow0 + 16 * 128;
    const int wofs = w * 1024;

    floatx4 acc[4][4];
#pragma unroll
    for (int i = 0; i < 4; ++i)
#pragma unroll
        for (int j = 0; j < 4; ++j) acc[i][j] = (floatx4)0.f;
    const int fr = lane & 15, fk = (lane >> 4) * 8;

    for (int k0 = 0; k0 < 128; k0 += 32) {
        __syncthreads();
        GLL16(xbf + xrow0 + k0, As + wofs);
        GLL16(xbf + xrow1 + k0, As + wofs + 512);
        GLL16(WW + brow0 + k0, Bs + wofs);
        GLL16(WW + brow1 + k0, Bs + wofs + 512);
        __syncthreads();
        short8 af[4], bf[4];
#pragma unroll
        for (int i = 0; i < 4; ++i) {
            af[i] = *(const short8*)&As[(mq + i * 16 + fr) * 32 + fk];
            bf[i] = *(const short8*)&Bs[(lq + i * 16 + fr) * 32 + fk];
        }
#pragma unroll
        for (int i = 0; i < 4; ++i)
#pragma unroll
            for (int j = 0; j < 4; ++j)
                acc[i][j] = __builtin_amdgcn_mfma_f32_16x16x32_bf16(
                    af[i], bf[j], acc[i][j], 0, 0, 0);
    }
#pragma unroll
    for (int i = 0; i < 4; ++i)
#pragma unroll
        for (int j = 0; j < 4; ++j)
#pragma unroll
            for (int r = 0; r < 4; ++r) {
                int c = c0 + mq + i * 16 + (lane >> 4) * 4 + r;
                int q = lq + j * 16 + (lane & 15);
                SEf[(((size_t)(c >> 6) * 512 + n) * 64 + (c & 63)) * 128 + q] =
                    f2bf(acc[i][j][r]);
            }
}

// ---------------------------------------------------------------------------
// Boundary scan: H[j+1] = z^T * H[j] + SE[j], H[0]=0; store H[j] (bf16).
// thread = (b,n,s).
// ---------------------------------------------------------------------------
__global__ __launch_bounds__(256) void bscan(const float* __restrict__ dAr,
                                             const float* __restrict__ dAi,
                                             const u16* __restrict__ SEf,
                                             u16* __restrict__ Ht) {
    const int id = blockIdx.x * 256 + threadIdx.x;
    const int s = id & 63, n = (id >> 6) & 511, b = id >> 15;
    const float a = dAr[n * 64 + s], wv = dAi[n * 64 + s];
    const float eaT = expf(a * 128.f);
    float sT, cT;
    sincosf(wv * 128.f, &sT, &cT);
    const float zTr = eaT * cT, zTi = eaT * sT;
    const size_t base = ((size_t)b * 512 + n) * 64 * 128;
    float Hr = 0.f, Hi = 0.f;
    for (int j = 0; j < 64; ++j) {
        Ht[base + j * 128 + s]      = f2bf(Hr);
        Ht[base + j * 128 + 64 + s] = f2bf(Hi);
        float ser = bf2f(SEf[base + j * 128 + s]);
        float sei = bf2f(SEf[base + j * 128 + 64 + s]);
        float nHr = fmaf(zTr, Hr, fmaf(-zTi, Hi, ser));
        float nHi = fmaf(zTi, Hr, fmaf(zTr, Hi, sei));
        Hr = nHr; Hi = nHi;
    }
}

// ---------------------------------------------------------------------------
// y-GEMM: per n, y[c][t] = sum_{k<128} x[c][k]*Toep[n][t][k]
//                        + sum_{k>=128} H[c][k-128]*M[n][t][k-128]
//   = [x ; H](c, k=0..255) dot Afull[n][t][k].  K = 256, cols t = 0..127.
// ---------------------------------------------------------------------------
__global__ __launch_bounds__(256) void y_gemm(const u16* __restrict__ xbf,
                                              const u16* __restrict__ Ht,
                                              const u16* __restrict__ Af,
                                              float* __restrict__ wy) {
    __shared__ u16 As[128 * 32];   // [x;H] rows (c)
    __shared__ u16 Bs[128 * 32];   // Afull rows (t)
    const int n  = blockIdx.y;
    const int c0 = blockIdx.x * 128;
    const int t  = threadIdx.x;
    const int w  = t >> 6, lane = t & 63;
    const int mq = (w >> 1) * 64;   // row (c) quadrant
    const int lq = (w & 1) * 64;    // col (t) quadrant
    const int ar0 = 32 * w + (lane >> 2);
    const int kq8 = (lane & 3) * 8;
    const int c_a0 = c0 + ar0, c_a1 = c_a0 + 16;
    const size_t xrow0 = ((size_t)(c_a0 >> 6) * 512 + n) * 8192 + (size_t)(c_a0 & 63) * 128 + kq8;
    const size_t xrow1 = ((size_t)(c_a1 >> 6) * 512 + n) * 8192 + (size_t)(c_a1 & 63) * 128 + kq8;
    const size_t hrow0 = (((size_t)(c_a0 >> 6) * 512 + n) * 64 + (c_a0 & 63)) * 128 + kq8;
    const size_t hrow1 = (((size_t)(c_a1 >> 6) * 512 + n) * 64 + (c_a1 & 63)) * 128 + kq8;
    const size_t brow0 = (size_t)n * 32768 + (size_t)ar0 * 256 + kq8;
    const size_t brow1 = brow0 + 16 * 256;
    const int wofs = w * 1024;

    floatx4 acc[4][4];
#pragma unroll
    for (int i = 0; i < 4; ++i)
#pragma unroll
        for (int j = 0; j < 4; ++j) acc[i][j] = (floatx4)0.f;
    const int fr = lane & 15, fk = (lane >> 4) * 8;

    for (int k0 = 0; k0 < 256; k0 += 32) {
        __syncthreads();
        if (k0 < 128) {
            GLL16(xbf + xrow0 + k0, As + wofs);
            GLL16(xbf + xrow1 + k0, As + wofs + 512);
        } else {
            GLL16(Ht + hrow0 + (k0 - 128), As + wofs);
            GLL16(Ht + hrow1 + (k0 - 128), As + wofs + 512);
        }
        GLL16(Af + brow0 + k0, Bs + wofs);
        GLL16(Af + brow1 + k0, Bs + wofs + 512);
        __syncthreads();
        short8 af[4], bf[4];
#pragma unroll
        for (int i = 0; i < 4; ++i) {
            af[i] = *(const short8*)&As[(mq + i * 16 + fr) * 32 + fk];
            bf[i] = *(const short8*)&Bs[(lq + i * 16 + fr) * 32 + fk];
        }
#pragma unroll
        for (int i = 0; i < 4; ++i)
#pragma unroll
            for (int j = 0; j < 4; ++j)
                acc[i][j] = __builtin_amdgcn_mfma_f32_16x16x32_bf16(
                    af[i], bf[j], acc[i][j], 0, 0, 0);
    }
#pragma unroll
    for (int i = 0; i < 4; ++i)
#pragma unroll
        for (int j = 0; j < 4; ++j)
#pragma unroll
            for (int r = 0; r < 4; ++r) {
                int c  = c0 + mq + i * 16 + (lane >> 4) * 4 + r;
                int tc = lq + j * 16 + (lane & 15);
                wy[((size_t)(c >> 6) * 512 + n) * 8192 + (size_t)(c & 63) * 128 + tc] =
                    acc[i][j][r];
            }
}

// ---------------------------------------------------------------------------
extern "C" void kernel_launch(void* const* d_in, const int* in_sizes, int n_in,
                              void* d_out, int out_size, void* d_ws, size_t ws_size,
                              hipStream_t stream) {
    const float* input = (const float*)d_in[0];  // [B, C, L]
    const float* dAr   = (const float*)d_in[1];
    const float* dAi   = (const float*)d_in[2];
    const float* Bm    = (const float*)d_in[3];  // [N, C]
    const float* Cm    = (const float*)d_in[4];  // [C, N]
    const float* E     = (const float*)d_in[5];
    float* out = (float*)d_out;

    char* ws = (char*)d_ws;
    u16*   xthi = (u16*)(ws + 0);            // 32 MB   (later: wy fp32 64MB over xthi+xtlo)
    u16*   xtlo = (u16*)(ws + 33554432);     // 32 MB
    u16*   xbf  = (u16*)(ws + 67108864);     // 32 MB   (later: ythi)
    u16*   Afu  = (u16*)(ws + 100663296);    // 32 MB   (later: ytlo)
    u16*   WW   = (u16*)(ws + 134217728);    // 16 MB
    u16*   SEf  = (u16*)(ws + 150994944);    // 32 MB
    u16*   Ht   = (u16*)(ws + 184549376);    // 32 MB
    float* Kn   = (float*)(ws + 218103808);  // 0.25 MB
    u16*   wbhi = (u16*)(ws + 218365952);
    u16*   wblo = (u16*)(ws + 218890240);
    u16*   wchi = (u16*)(ws + 219414528);
    u16*   wclo = (u16*)(ws + 219938816);
    float* wy   = (float*)(ws + 0);
    u16*   ythi = xbf;
    u16*   ytlo = Afu;

    convert_split2<<<512, 256, 0, stream>>>(Bm, Cm, wbhi, wblo, wchi, wclo);
    kern_K<<<256, 256, 0, stream>>>(dAr, dAi, E, Kn);
    kern_AW<<<98304, 256, 0, stream>>>(dAr, dAi, E, Kn, Afu, WW);
    transpose_split<<<dim3(128, 8, BSZ), 256, 0, stream>>>(input, xthi, xtlo);
    gemm_mfma_bf16<<<dim3(64, 4, BSZ), 256, 0, stream>>>(wbhi, wblo, xthi, xtlo, xbf);
    se_gemm<<<dim3(2, 512), 256, 0, stream>>>(xbf, WW, SEf);
    bscan<<<512, 256, 0, stream>>>(dAr, dAi, SEf, Ht);
    y_gemm<<<dim3(2, 512), 256, 0, stream>>>(xbf, Ht, Afu, wy);
    transpose_split<<<dim3(128, 8, BSZ), 256, 0, stream>>>(wy, ythi, ytlo);
    gemm_mfma_f32<<<dim3(64, 4, BSZ), 256, 0, stream>>>(wchi, wclo, ythi, ytlo, out);
}

// Round 5
// 273.277 us; speedup vs baseline: 2.3641x; 1.4579x over previous
//
#include <hip/hip_runtime.h>
#include <hip/hip_bf16.h>

typedef unsigned short u16;
typedef __attribute__((ext_vector_type(8))) short short8;
typedef __attribute__((ext_vector_type(8))) unsigned short ushort8v;
typedef __attribute__((ext_vector_type(4))) float floatx4;

#define BSZ   4
#define CDIM  512
#define NDIM  512
#define SDIM  64
#define LEN   8192

__device__ __forceinline__ u16 f2bf(float x) {
    unsigned int u = __float_as_uint(x);
    unsigned int r = (u + 0x7FFFu + ((u >> 16) & 1u)) >> 16;
    return (u16)r;
}

#define GLL16(g, l)                                                          \
    __builtin_amdgcn_global_load_lds(                                        \
        (const __attribute__((address_space(1))) unsigned int*)(g),          \
        (__attribute__((address_space(3))) unsigned int*)(l), 16, 0, 0)

// ---------------------------------------------------------------------------
// Both weight matrices fp32 -> bf16 (plain cast, no split).
// ---------------------------------------------------------------------------
__global__ __launch_bounds__(256) void convert_w(const float* __restrict__ B,
                                                 const float* __restrict__ C,
                                                 u16* __restrict__ bh,
                                                 u16* __restrict__ ch) {
    int i = (blockIdx.x * 256 + threadIdx.x) * 4;
    const float* s; u16* d;
    if (i < 262144) { s = B; d = bh; }
    else            { s = C; d = ch; i -= 262144; }
    float4 v = *(const float4*)&s[i];
    ushort4 h;
    u16* hp = (u16*)&h;
    hp[0] = f2bf(v.x); hp[1] = f2bf(v.y); hp[2] = f2bf(v.z); hp[3] = f2bf(v.w);
    *(ushort4*)&d[i] = h;
}

// ---------------------------------------------------------------------------
// Per-n prep (block = n): fill Af [n][t=128][k=256] and WW [n][q=128][tau=128].
//  Af k>=128 (M-part): s=k-128 (<64): E*e^{a(t+1)}cos(w(t+1)); s+192: -E*e*sin
//  Kn[d] = row-sum of M fp32 (d=t+1), Kn[0] = sum_s E
//  Af k<128 (Toeplitz): K[t-k] for k<=t else 0
//  WW[q=s][tau] = e^{a d}cos(w d), WW[s+64][tau] = e^{a d}sin(w d), d=127-tau
// ---------------------------------------------------------------------------
__global__ __launch_bounds__(256) void prep_nw(const float* __restrict__ dAr,
                                               const float* __restrict__ dAi,
                                               const float* __restrict__ E,
                                               u16* __restrict__ Af,
                                               u16* __restrict__ WW) {
    __shared__ float sA[64], sW[64], sE[64];
    __shared__ float Ms[128][65];
    __shared__ float sK[128];
    const int n = blockIdx.x;
    const int t = threadIdx.x;
    if (t < 64) {
        sA[t] = dAr[n * 64 + t];
        sW[t] = dAi[n * 64 + t];
        sE[t] = E[n * 64 + t];
    }
    __syncthreads();
    u16* Afn = Af + (size_t)n * 32768;
    // M-part: 128 t x 64 s = 8192 pairs, 32 iters
#pragma unroll 4
    for (int it = 0; it < 32; ++it) {
        int idx = it * 256 + t;
        int tt = idx >> 6, s = idx & 63;
        float a = sA[s], w = sW[s], e = sE[s];
        float tp1 = (float)(tt + 1);
        float sn, cs;
        __sincosf(w * tp1, &sn, &cs);
        float ea = __expf(a * tp1) * e;
        float mr = ea * cs;
        Ms[tt][s] = mr;
        Afn[tt * 256 + 128 + s] = f2bf(mr);
        Afn[tt * 256 + 192 + s] = f2bf(-ea * sn);
    }
    __syncthreads();
    if (t < 128) {
        float acc = 0.f;
        if (t == 0) {
#pragma unroll
            for (int s = 0; s < 64; ++s) acc += sE[s];
        } else {
#pragma unroll
            for (int s = 0; s < 64; ++s) acc += Ms[t - 1][s];
        }
        sK[t] = acc;
    }
    __syncthreads();
    // Toeplitz: 128 t x 128 k = 16384, 64 iters
#pragma unroll 8
    for (int it = 0; it < 64; ++it) {
        int idx = it * 256 + t;
        int tt = idx >> 7, k = idx & 127;
        float v = (k <= tt) ? sK[tt - k] : 0.f;
        Afn[tt * 256 + k] = f2bf(v);
    }
    // WW: 64 s x 128 tau = 8192 pairs, 32 iters
    u16* WWn = WW + (size_t)n * 16384;
#pragma unroll 4
    for (int it = 0; it < 32; ++it) {
        int idx = it * 256 + t;
        int s = idx >> 7, tau = idx & 127;
        float a = sA[s], w = sW[s];
        float d = (float)(127 - tau);
        float sn, cs;
        __sincosf(w * d, &sn, &cs);
        float ea = __expf(a * d);
        WWn[s * 128 + tau] = f2bf(ea * cs);
        WWn[(s + 64) * 128 + tau] = f2bf(ea * sn);
    }
}

// ---------------------------------------------------------------------------
// Transpose input: src [B][512][8192] fp32 -> dst [B][8192][512] bf16.
// ---------------------------------------------------------------------------
__global__ __launch_bounds__(256) void transpose_in(const float* __restrict__ src,
                                                    u16* __restrict__ dst) {
    __shared__ float tile[64][65];
    const int b  = blockIdx.z;
    const int r0 = blockIdx.y * 64;
    const int c0 = blockIdx.x * 64;
    const int t  = threadIdx.x;
    const float* s = src + (size_t)b * 512 * 8192;
#pragma unroll
    for (int p = 0; p < 4; ++p) {
        int r = (t >> 4) + p * 16;
        float4 v = *(const float4*)&s[(size_t)(r0 + r) * 8192 + c0 + (t & 15) * 4];
        tile[r][(t & 15) * 4 + 0] = v.x;
        tile[r][(t & 15) * 4 + 1] = v.y;
        tile[r][(t & 15) * 4 + 2] = v.z;
        tile[r][(t & 15) * 4 + 3] = v.w;
    }
    __syncthreads();
#pragma unroll
    for (int p = 0; p < 4; ++p) {
        int i  = (t >> 4) + p * 16;
        int cb = (t & 15) * 4;
        ushort4 h;
        u16* hp = (u16*)&h;
#pragma unroll
        for (int q = 0; q < 4; ++q) hp[q] = f2bf(tile[cb + q][i]);
        *(ushort4*)&dst[((size_t)b * 8192 + c0 + i) * 512 + r0 + cb] = h;
    }
}

// ---------------------------------------------------------------------------
// Transpose u16: src [B][512][8192] -> dst [B][8192][512].
// ---------------------------------------------------------------------------
__global__ __launch_bounds__(256) void transpose_u16(const u16* __restrict__ src,
                                                     u16* __restrict__ dst) {
    __shared__ u16 tile[64][72];   // 144 B rows (16B-aligned)
    const int b  = blockIdx.z;
    const int n0 = blockIdx.y * 64;
    const int l0 = blockIdx.x * 64;
    const int t  = threadIdx.x;
    const u16* s = src + (size_t)b * 512 * 8192;
    u16* d = dst + (size_t)b * 8192 * 512;
#pragma unroll
    for (int p = 0; p < 2; ++p) {
        int r = (t >> 3) + p * 32;
        *(ushort8v*)&tile[r][(t & 7) * 8] =
            *(const ushort8v*)&s[(size_t)(n0 + r) * 8192 + l0 + (t & 7) * 8];
    }
    __syncthreads();
#pragma unroll
    for (int p = 0; p < 2; ++p) {
        int li = (t >> 3) + p * 32;
        int cb = (t & 7) * 8;
        ushort8v v;
#pragma unroll
        for (int q = 0; q < 8; ++q) v[q] = tile[cb + q][li];
        *(ushort8v*)&d[(size_t)(l0 + li) * 512 + n0 + cb] = v;
    }
}

// ---------------------------------------------------------------------------
// Pure-bf16 MFMA GEMM, bf16 output: Y[b][m][l] = sum_k A[m][k]*Xt[b][l][k]
// ---------------------------------------------------------------------------
__global__ __launch_bounds__(256) void gemm_bf16_o16(const u16* __restrict__ A,
                                                     const u16* __restrict__ Xt,
                                                     u16* __restrict__ Y) {
    __shared__ u16 As[128 * 32];
    __shared__ u16 Xs[128 * 32];
    const int b    = blockIdx.z;
    const int m0   = blockIdx.y * 128;
    const int l0   = blockIdx.x * 128;
    const int t    = threadIdx.x;
    const int w    = t >> 6;
    const int lane = t & 63;
    const int mq   = (w >> 1) * 64;
    const int lq   = (w & 1) * 64;
    const u16* Xb = Xt + (size_t)b * 8192 * 512;
    const size_t a_off = (size_t)(m0 + 32 * w + (lane >> 2)) * 512 + (lane & 3) * 8;
    const size_t x_off = (size_t)(l0 + 32 * w + (lane >> 2)) * 512 + (lane & 3) * 8;
    u16* AsW = As + w * 1024;
    u16* XsW = Xs + w * 1024;

    floatx4 acc[4][4];
#pragma unroll
    for (int i = 0; i < 4; ++i)
#pragma unroll
        for (int j = 0; j < 4; ++j) acc[i][j] = (floatx4)0.f;
    const int fr = lane & 15;
    const int fk = (lane >> 4) * 8;

    for (int k0 = 0; k0 < 512; k0 += 32) {
        __syncthreads();
        GLL16(A + a_off + k0, AsW);
        GLL16(A + a_off + 16 * 512 + k0, AsW + 512);
        GLL16(Xb + x_off + k0, XsW);
        GLL16(Xb + x_off + 16 * 512 + k0, XsW + 512);
        __syncthreads();
        short8 af[4], bf[4];
#pragma unroll
        for (int i = 0; i < 4; ++i) {
            af[i] = *(const short8*)&As[(mq + i * 16 + fr) * 32 + fk];
            bf[i] = *(const short8*)&Xs[(lq + i * 16 + fr) * 32 + fk];
        }
#pragma unroll
        for (int i = 0; i < 4; ++i)
#pragma unroll
            for (int j = 0; j < 4; ++j)
                acc[i][j] = __builtin_amdgcn_mfma_f32_16x16x32_bf16(
                    af[i], bf[j], acc[i][j], 0, 0, 0);
    }
    u16* Yb = Y + (size_t)b * 512 * 8192;
#pragma unroll
    for (int i = 0; i < 4; ++i)
#pragma unroll
        for (int j = 0; j < 4; ++j)
#pragma unroll
            for (int r = 0; r < 4; ++r) {
                int mg = m0 + mq + i * 16 + (lane >> 4) * 4 + r;
                int lg = l0 + lq + j * 16 + (lane & 15);
                Yb[(size_t)mg * 8192 + lg] = f2bf(acc[i][j][r]);
            }
}

// ---------------------------------------------------------------------------
// Pure-bf16 MFMA GEMM, fp32 output (final projection).
// ---------------------------------------------------------------------------
__global__ __launch_bounds__(256) void gemm_bf16_o32(const u16* __restrict__ A,
                                                     const u16* __restrict__ Xt,
                                                     float* __restrict__ Y) {
    __shared__ u16 As[128 * 32];
    __shared__ u16 Xs[128 * 32];
    const int b    = blockIdx.z;
    const int m0   = blockIdx.y * 128;
    const int l0   = blockIdx.x * 128;
    const int t    = threadIdx.x;
    const int w    = t >> 6;
    const int lane = t & 63;
    const int mq   = (w >> 1) * 64;
    const int lq   = (w & 1) * 64;
    const u16* Xb = Xt + (size_t)b * 8192 * 512;
    const size_t a_off = (size_t)(m0 + 32 * w + (lane >> 2)) * 512 + (lane & 3) * 8;
    const size_t x_off = (size_t)(l0 + 32 * w + (lane >> 2)) * 512 + (lane & 3) * 8;
    u16* AsW = As + w * 1024;
    u16* XsW = Xs + w * 1024;

    floatx4 acc[4][4];
#pragma unroll
    for (int i = 0; i < 4; ++i)
#pragma unroll
        for (int j = 0; j < 4; ++j) acc[i][j] = (floatx4)0.f;
    const int fr = lane & 15;
    const int fk = (lane >> 4) * 8;

    for (int k0 = 0; k0 < 512; k0 += 32) {
        __syncthreads();
        GLL16(A + a_off + k0, AsW);
        GLL16(A + a_off + 16 * 512 + k0, AsW + 512);
        GLL16(Xb + x_off + k0, XsW);
        GLL16(Xb + x_off + 16 * 512 + k0, XsW + 512);
        __syncthreads();
        short8 af[4], bf[4];
#pragma unroll
        for (int i = 0; i < 4; ++i) {
            af[i] = *(const short8*)&As[(mq + i * 16 + fr) * 32 + fk];
            bf[i] = *(const short8*)&Xs[(lq + i * 16 + fr) * 32 + fk];
        }
#pragma unroll
        for (int i = 0; i < 4; ++i)
#pragma unroll
            for (int j = 0; j < 4; ++j)
                acc[i][j] = __builtin_amdgcn_mfma_f32_16x16x32_bf16(
                    af[i], bf[j], acc[i][j], 0, 0, 0);
    }
    float* Yb = Y + (size_t)b * 512 * 8192;
#pragma unroll
    for (int i = 0; i < 4; ++i)
#pragma unroll
        for (int j = 0; j < 4; ++j)
#pragma unroll
            for (int r = 0; r < 4; ++r) {
                int mg = m0 + mq + i * 16 + (lane >> 4) * 4 + r;
                int lg = l0 + lq + j * 16 + (lane & 15);
                Yb[(size_t)mg * 8192 + lg] = acc[i][j][r];
            }
}

// ---------------------------------------------------------------------------
// SE-GEMM: per n, SE[c][q] = sum_tau x[c][tau] * WW[n][q][tau]
// ---------------------------------------------------------------------------
__global__ __launch_bounds__(256) void se_gemm(const u16* __restrict__ xbf,
                                               const u16* __restrict__ WW,
                                               u16* __restrict__ SEf) {
    __shared__ u16 As[128 * 32];
    __shared__ u16 Bs[128 * 32];
    const int n  = blockIdx.y;
    const int c0 = blockIdx.x * 128;
    const int t  = threadIdx.x;
    const int w  = t >> 6, lane = t & 63;
    const int mq = (w >> 1) * 64;
    const int lq = (w & 1) * 64;
    const int ar0 = 32 * w + (lane >> 2);
    const int kq8 = (lane & 3) * 8;
    const int c_a0 = c0 + ar0, c_a1 = c_a0 + 16;
    const size_t xrow0 = ((size_t)(c_a0 >> 6) * 512 + n) * 8192 + (size_t)(c_a0 & 63) * 128 + kq8;
    const size_t xrow1 = ((size_t)(c_a1 >> 6) * 512 + n) * 8192 + (size_t)(c_a1 & 63) * 128 + kq8;
    const size_t brow0 = (size_t)n * 16384 + (size_t)ar0 * 128 + kq8;
    const size_t brow1 = brow0 + 16 * 128;
    const int wofs = w * 1024;

    floatx4 acc[4][4];
#pragma unroll
    for (int i = 0; i < 4; ++i)
#pragma unroll
        for (int j = 0; j < 4; ++j) acc[i][j] = (floatx4)0.f;
    const int fr = lane & 15, fk = (lane >> 4) * 8;

    for (int k0 = 0; k0 < 128; k0 += 32) {
        __syncthreads();
        GLL16(xbf + xrow0 + k0, As + wofs);
        GLL16(xbf + xrow1 + k0, As + wofs + 512);
        GLL16(WW + brow0 + k0, Bs + wofs);
        GLL16(WW + brow1 + k0, Bs + wofs + 512);
        __syncthreads();
        short8 af[4], bf[4];
#pragma unroll
        for (int i = 0; i < 4; ++i) {
            af[i] = *(const short8*)&As[(mq + i * 16 + fr) * 32 + fk];
            bf[i] = *(const short8*)&Bs[(lq + i * 16 + fr) * 32 + fk];
        }
#pragma unroll
        for (int i = 0; i < 4; ++i)
#pragma unroll
            for (int j = 0; j < 4; ++j)
                acc[i][j] = __builtin_amdgcn_mfma_f32_16x16x32_bf16(
                    af[i], bf[j], acc[i][j], 0, 0, 0);
    }
#pragma unroll
    for (int i = 0; i < 4; ++i)
#pragma unroll
        for (int j = 0; j < 4; ++j)
#pragma unroll
            for (int r = 0; r < 4; ++r) {
                int c = c0 + mq + i * 16 + (lane >> 4) * 4 + r;
                int q = lq + j * 16 + (lane & 15);
                SEf[(((size_t)(c >> 6) * 512 + n) * 64 + (c & 63)) * 128 + q] =
                    f2bf(acc[i][j][r]);
            }
}

// ---------------------------------------------------------------------------
// Boundary scan: H[j+1] = z^T * H[j] + SE[j], H[0]=0; store H[j] (bf16).
// ---------------------------------------------------------------------------
__global__ __launch_bounds__(256) void bscan(const float* __restrict__ dAr,
                                             const float* __restrict__ dAi,
                                             const u16* __restrict__ SEf,
                                             u16* __restrict__ Ht) {
    const int id = blockIdx.x * 256 + threadIdx.x;
    const int s = id & 63, n = (id >> 6) & 511, b = id >> 15;
    const float a = dAr[n * 64 + s], wv = dAi[n * 64 + s];
    const float eaT = expf(a * 128.f);
    float sT, cT;
    sincosf(wv * 128.f, &sT, &cT);
    const float zTr = eaT * cT, zTi = eaT * sT;
    const size_t base = ((size_t)b * 512 + n) * 64 * 128;
    float Hr = 0.f, Hi = 0.f;
    for (int j = 0; j < 64; ++j) {
        Ht[base + j * 128 + s]      = f2bf(Hr);
        Ht[base + j * 128 + 64 + s] = f2bf(Hi);
        float ser = __uint_as_float((unsigned int)SEf[base + j * 128 + s] << 16);
        float sei = __uint_as_float((unsigned int)SEf[base + j * 128 + 64 + s] << 16);
        float nHr = fmaf(zTr, Hr, fmaf(-zTi, Hi, ser));
        float nHi = fmaf(zTi, Hr, fmaf(zTr, Hi, sei));
        Hr = nHr; Hi = nHi;
    }
}

// ---------------------------------------------------------------------------
// y-GEMM: y[c][t] = [x ; H](c, k) dot Afull[n][t][k], K=256. bf16 output.
// ---------------------------------------------------------------------------
__global__ __launch_bounds__(256) void y_gemm(const u16* __restrict__ xbf,
                                              const u16* __restrict__ Ht,
                                              const u16* __restrict__ Af,
                                              u16* __restrict__ wyb) {
    __shared__ u16 As[128 * 32];
    __shared__ u16 Bs[128 * 32];
    const int n  = blockIdx.y;
    const int c0 = blockIdx.x * 128;
    const int t  = threadIdx.x;
    const int w  = t >> 6, lane = t & 63;
    const int mq = (w >> 1) * 64;
    const int lq = (w & 1) * 64;
    const int ar0 = 32 * w + (lane >> 2);
    const int kq8 = (lane & 3) * 8;
    const int c_a0 = c0 + ar0, c_a1 = c_a0 + 16;
    const size_t xrow0 = ((size_t)(c_a0 >> 6) * 512 + n) * 8192 + (size_t)(c_a0 & 63) * 128 + kq8;
    const size_t xrow1 = ((size_t)(c_a1 >> 6) * 512 + n) * 8192 + (size_t)(c_a1 & 63) * 128 + kq8;
    const size_t hrow0 = (((size_t)(c_a0 >> 6) * 512 + n) * 64 + (c_a0 & 63)) * 128 + kq8;
    const size_t hrow1 = (((size_t)(c_a1 >> 6) * 512 + n) * 64 + (c_a1 & 63)) * 128 + kq8;
    const size_t brow0 = (size_t)n * 32768 + (size_t)ar0 * 256 + kq8;
    const size_t brow1 = brow0 + 16 * 256;
    const int wofs = w * 1024;

    floatx4 acc[4][4];
#pragma unroll
    for (int i = 0; i < 4; ++i)
#pragma unroll
        for (int j = 0; j < 4; ++j) acc[i][j] = (floatx4)0.f;
    const int fr = lane & 15, fk = (lane >> 4) * 8;

    for (int k0 = 0; k0 < 256; k0 += 32) {
        __syncthreads();
        if (k0 < 128) {
            GLL16(xbf + xrow0 + k0, As + wofs);
            GLL16(xbf + xrow1 + k0, As + wofs + 512);
        } else {
            GLL16(Ht + hrow0 + (k0 - 128), As + wofs);
            GLL16(Ht + hrow1 + (k0 - 128), As + wofs + 512);
        }
        GLL16(Af + brow0 + k0, Bs + wofs);
        GLL16(Af + brow1 + k0, Bs + wofs + 512);
        __syncthreads();
        short8 af[4], bf[4];
#pragma unroll
        for (int i = 0; i < 4; ++i) {
            af[i] = *(const short8*)&As[(mq + i * 16 + fr) * 32 + fk];
            bf[i] = *(const short8*)&Bs[(lq + i * 16 + fr) * 32 + fk];
        }
#pragma unroll
        for (int i = 0; i < 4; ++i)
#pragma unroll
            for (int j = 0; j < 4; ++j)
                acc[i][j] = __builtin_amdgcn_mfma_f32_16x16x32_bf16(
                    af[i], bf[j], acc[i][j], 0, 0, 0);
    }
#pragma unroll
    for (int i = 0; i < 4; ++i)
#pragma unroll
        for (int j = 0; j < 4; ++j)
#pragma unroll
            for (int r = 0; r < 4; ++r) {
                int c  = c0 + mq + i * 16 + (lane >> 4) * 4 + r;
                int tc = lq + j * 16 + (lane & 15);
                wyb[((size_t)(c >> 6) * 512 + n) * 8192 + (size_t)(c & 63) * 128 + tc] =
                    f2bf(acc[i][j][r]);
            }
}

// ---------------------------------------------------------------------------
extern "C" void kernel_launch(void* const* d_in, const int* in_sizes, int n_in,
                              void* d_out, int out_size, void* d_ws, size_t ws_size,
                              hipStream_t stream) {
    const float* input = (const float*)d_in[0];  // [B, C, L]
    const float* dAr   = (const float*)d_in[1];
    const float* dAi   = (const float*)d_in[2];
    const float* Bm    = (const float*)d_in[3];  // [N, C]
    const float* Cm    = (const float*)d_in[4];  // [C, N]
    const float* E     = (const float*)d_in[5];
    float* out = (float*)d_out;

    char* ws = (char*)d_ws;
    const size_t MB = 1048576;
    u16* xt   = (u16*)(ws + 0);          // 32 MB  (later overlaid by wyb)
    u16* xbf  = (u16*)(ws + 32 * MB);    // 32 MB  (later overlaid by yt)
    u16* Af   = (u16*)(ws + 64 * MB);    // 32 MB
    u16* WW   = (u16*)(ws + 96 * MB);    // 16 MB
    u16* SEf  = (u16*)(ws + 112 * MB);   // 32 MB
    u16* Ht   = (u16*)(ws + 144 * MB);   // 32 MB
    u16* Bmb  = (u16*)(ws + 176 * MB);   // 0.5 MB
    u16* Cmb  = (u16*)(ws + 177 * MB);   // 0.5 MB
    u16* wyb  = xt;                      // overlay (xt dead after gemm1)
    u16* yt   = xbf;                     // overlay (xbf dead after y_gemm)

    convert_w<<<512, 256, 0, stream>>>(Bm, Cm, Bmb, Cmb);
    prep_nw<<<512, 256, 0, stream>>>(dAr, dAi, E, Af, WW);
    transpose_in<<<dim3(128, 8, BSZ), 256, 0, stream>>>(input, xt);
    gemm_bf16_o16<<<dim3(64, 4, BSZ), 256, 0, stream>>>(Bmb, xt, xbf);
    se_gemm<<<dim3(2, 512), 256, 0, stream>>>(xbf, WW, SEf);
    bscan<<<512, 256, 0, stream>>>(dAr, dAi, SEf, Ht);
    y_gemm<<<dim3(2, 512), 256, 0, stream>>>(xbf, Ht, Af, wyb);
    transpose_u16<<<dim3(128, 8, BSZ), 256, 0, stream>>>(wyb, yt);
    gemm_bf16_o32<<<dim3(64, 4, BSZ), 256, 0, stream>>>(Cmb, yt, out);
}